// Round 1
// baseline (618.706 us; speedup 1.0000x reference)
//
#include <hip/hip_runtime.h>
#include <hip/hip_bf16.h>

#define H  1024
#define L  4096
#define V  50257
#define H3 3072

// workspace layout (floats)
#define OFF_QW     0                    // 1024   query @ Wq
#define OFF_SCORES 1024                 // 4096   scores -> attn (in place)
#define OFF_X      (1024 + 4096)        // 2048   x = concat(context, emb_relu)
#define OFF_GI0    (OFF_X + 2048)       // 3072
#define OFF_GH0    (OFF_GI0 + 3072)     // 3072
#define OFF_GI1    (OFF_GH0 + 3072)     // 3072
#define OFF_GH1    (OFF_GI1 + 3072)     // 3072
#define OFF_LOGITS (OFF_GH1 + 3072)     // V
#define WS_FLOATS  (OFF_LOGITS + V)

// ---------------- embedding + relu -> x[H..2H) ----------------
__global__ __launch_bounds__(256) void k_embed(const int* __restrict__ tok,
                                               const float* __restrict__ emb,
                                               float* __restrict__ ws) {
    int j = blockIdx.x * 256 + threadIdx.x;
    int t = tok[0];
    float v = emb[(size_t)t * H + j];
    ws[OFF_X + H + j] = fmaxf(v, 0.f);
}

// ---------------- qW[j] = sum_i q[i] * Wq[i*H + j] ----------------
// grid (4, 16): 4 j-blocks x 16 k-splits of 64
__global__ __launch_bounds__(256) void k_qw(const float* __restrict__ Wq,
                                            const float* __restrict__ hid,
                                            float* __restrict__ ws) {
    int j = blockIdx.x * 256 + threadIdx.x;
    const float* q = hid + H;   // last-layer hidden
    int i0 = blockIdx.y * 64;
    float acc = 0.f;
#pragma unroll 8
    for (int i = i0; i < i0 + 64; ++i) acc += q[i] * Wq[i * H + j];
    atomicAdd(&ws[OFF_QW + j], acc);
}

// ---------------- scores: tanh(qW + enc@Wk) @ wv ----------------
// fp32 register-tiled GEMM: 64x64 tile per block, 4x4 per thread, BK=32.
// grid (L/64=64, H/64=16), block 256 (16x16).
__global__ __launch_bounds__(256) void k_gemm_scores(const float* __restrict__ enc,
                                                     const float* __restrict__ Wk,
                                                     const float* __restrict__ wv,
                                                     float* __restrict__ ws) {
    __shared__ float As[32][68];   // As[k][r] (transposed), 68: 16B-aligned rows, conflict-light
    __shared__ float Bs[32][68];   // Bs[k][n]
    const int tid = threadIdx.x;
    const int tx = tid & 15, ty = tid >> 4;
    const int m0 = blockIdx.x * 64, n0 = blockIdx.y * 64;

    float acc[4][4] = {};

    for (int k0 = 0; k0 < H; k0 += 32) {
        // stage A (enc rows) transposed into As[k][r]
#pragma unroll
        for (int s = 0; s < 2; ++s) {
            int u  = tid + s * 256;      // 0..511
            int r  = u >> 3;             // 0..63
            int kq = u & 7;              // 0..7
            float4 a = *(const float4*)(enc + (m0 + r) * H + k0 + kq * 4);
            As[kq * 4 + 0][r] = a.x;
            As[kq * 4 + 1][r] = a.y;
            As[kq * 4 + 2][r] = a.z;
            As[kq * 4 + 3][r] = a.w;
        }
        // stage B (Wk) natural layout Bs[k][n]
#pragma unroll
        for (int s = 0; s < 2; ++s) {
            int u  = tid + s * 256;
            int k  = u >> 4;             // 0..31
            int nq = u & 15;             // 0..15
            *(float4*)(&Bs[k][nq * 4]) = *(const float4*)(Wk + (k0 + k) * H + n0 + nq * 4);
        }
        __syncthreads();
#pragma unroll
        for (int k = 0; k < 32; ++k) {
            float4 a = *(const float4*)(&As[k][ty * 4]);
            float4 b = *(const float4*)(&Bs[k][tx * 4]);
            acc[0][0] += a.x * b.x; acc[0][1] += a.x * b.y; acc[0][2] += a.x * b.z; acc[0][3] += a.x * b.w;
            acc[1][0] += a.y * b.x; acc[1][1] += a.y * b.y; acc[1][2] += a.y * b.z; acc[1][3] += a.y * b.w;
            acc[2][0] += a.z * b.x; acc[2][1] += a.z * b.y; acc[2][2] += a.z * b.z; acc[2][3] += a.z * b.w;
            acc[3][0] += a.w * b.x; acc[3][1] += a.w * b.y; acc[3][2] += a.w * b.z; acc[3][3] += a.w * b.w;
        }
        __syncthreads();
    }

    // epilogue: tanh(feat + qW) * wv, reduce over this block's 64 columns
    float4 qw4 = *(const float4*)(&ws[OFF_QW + n0 + tx * 4]);
    float4 wv4 = *(const float4*)(wv + n0 + tx * 4);
#pragma unroll
    for (int i = 0; i < 4; ++i) {
        float s = tanhf(acc[i][0] + qw4.x) * wv4.x
                + tanhf(acc[i][1] + qw4.y) * wv4.y
                + tanhf(acc[i][2] + qw4.z) * wv4.z
                + tanhf(acc[i][3] + qw4.w) * wv4.w;
#pragma unroll
        for (int off = 1; off < 16; off <<= 1) s += __shfl_down(s, off, 16);
        if (tx == 0) atomicAdd(&ws[OFF_SCORES + m0 + ty * 4 + i], s);
    }
}

// ---------------- softmax over L (in place) ----------------
__global__ __launch_bounds__(1024) void k_softmax(float* __restrict__ ws) {
    __shared__ float red[16];
    const int tid = threadIdx.x;
    float* sc = ws + OFF_SCORES;

    float m = -1e30f;
    for (int l = tid; l < L; l += 1024) m = fmaxf(m, sc[l]);
#pragma unroll
    for (int off = 32; off; off >>= 1) m = fmaxf(m, __shfl_down(m, off));
    if ((tid & 63) == 0) red[tid >> 6] = m;
    __syncthreads();
    if (tid == 0) {
        float mm = red[0];
        for (int w = 1; w < 16; ++w) mm = fmaxf(mm, red[w]);
        red[0] = mm;
    }
    __syncthreads();
    m = red[0];
    __syncthreads();

    float ssum = 0.f;
    for (int l = tid; l < L; l += 1024) ssum += expf(sc[l] - m);
#pragma unroll
    for (int off = 32; off; off >>= 1) ssum += __shfl_down(ssum, off);
    if ((tid & 63) == 0) red[tid >> 6] = ssum;
    __syncthreads();
    if (tid == 0) {
        float t = 0.f;
        for (int w = 0; w < 16; ++w) t += red[w];
        red[0] = t;
    }
    __syncthreads();
    float inv = 1.f / red[0];

    for (int l = tid; l < L; l += 1024) sc[l] = expf(sc[l] - m) * inv;
}

// ---------------- context[h] = sum_l attn[l] * enc[l][h] -> x[0..H) ----------------
// grid (4, 32) l-splits of 128
__global__ __launch_bounds__(256) void k_context(const float* __restrict__ enc,
                                                 float* __restrict__ ws) {
    int h = blockIdx.x * 256 + threadIdx.x;
    const float* attn = ws + OFF_SCORES;
    int l0 = blockIdx.y * 128;
    float acc = 0.f;
#pragma unroll 4
    for (int l = l0; l < l0 + 128; ++l) acc += attn[l] * enc[l * H + h];
    atomicAdd(&ws[OFF_X + h], acc);
}

// ---------------- GRU gates: gi = Wih@x + bih ; gh = Whh@h + bhh ----------------
// grid 1536: blocks [0,768) -> gi rows, [768,1536) -> gh rows; wave-per-row float4
__global__ __launch_bounds__(256) void k_gates(const float* __restrict__ Wih,
                                               const float* __restrict__ Whh,
                                               const float* __restrict__ bih,
                                               const float* __restrict__ bhh,
                                               const float* __restrict__ x, int Cx,
                                               const float* __restrict__ h,
                                               float* __restrict__ gi,
                                               float* __restrict__ gh) {
    int b = blockIdx.x;
    bool isH = (b >= 768);
    int row  = (isH ? b - 768 : b) * 4 + (threadIdx.x >> 6);
    int lane = threadIdx.x & 63;
    const float* W    = isH ? Whh : Wih;
    const float* v    = isH ? h : x;
    const float* bias = isH ? bhh : bih;
    int C       = isH ? H : Cx;
    float* out  = isH ? gh : gi;

    const float4* Wr = (const float4*)(W + (size_t)row * C);
    const float4* v4 = (const float4*)v;
    float acc = 0.f;
    int n4 = C >> 2;
    for (int c = lane; c < n4; c += 64) {
        float4 w = Wr[c], xx = v4[c];
        acc += w.x * xx.x + w.y * xx.y + w.z * xx.z + w.w * xx.w;
    }
#pragma unroll
    for (int off = 32; off; off >>= 1) acc += __shfl_down(acc, off);
    if (lane == 0) out[row] = acc + bias[row];
}

// ---------------- GRU combine: h' = (1-z)*n + z*h ----------------
__global__ __launch_bounds__(256) void k_combine(const float* __restrict__ gi,
                                                 const float* __restrict__ gh,
                                                 const float* __restrict__ h,
                                                 float* __restrict__ hout) {
    int j = blockIdx.x * 256 + threadIdx.x;
    float r = 1.f / (1.f + expf(-(gi[j] + gh[j])));
    float z = 1.f / (1.f + expf(-(gi[H + j] + gh[H + j])));
    float n = tanhf(gi[2 * H + j] + r * gh[2 * H + j]);
    hout[j] = (1.f - z) * n + z * h[j];
}

// ---------------- logits[v] = bd[v] + sum_k h1[k] * Wd[k*V + v] ----------------
// grid (ceil(V/256)=197, 8 k-splits of 128)
__global__ __launch_bounds__(256) void k_logits(const float* __restrict__ Wd,
                                                const float* __restrict__ bd,
                                                const float* __restrict__ h1,
                                                float* __restrict__ ws) {
    int v = blockIdx.x * 256 + threadIdx.x;
    if (v >= V) return;
    int k0 = blockIdx.y * 128;
    float acc = (blockIdx.y == 0) ? bd[v] : 0.f;
#pragma unroll 4
    for (int k = k0; k < k0 + 128; ++k) acc += h1[k] * Wd[(size_t)k * V + v];
    atomicAdd(&ws[OFF_LOGITS + v], acc);
}

// ---------------- log_softmax over V -> out[0..V) ----------------
__global__ __launch_bounds__(1024) void k_logsoftmax(const float* __restrict__ lg,
                                                     float* __restrict__ out) {
    __shared__ float red[16];
    const int tid = threadIdx.x;

    float m = -1e30f;
    for (int v = tid; v < V; v += 1024) m = fmaxf(m, lg[v]);
#pragma unroll
    for (int off = 32; off; off >>= 1) m = fmaxf(m, __shfl_down(m, off));
    if ((tid & 63) == 0) red[tid >> 6] = m;
    __syncthreads();
    if (tid == 0) {
        float mm = red[0];
        for (int w = 1; w < 16; ++w) mm = fmaxf(mm, red[w]);
        red[0] = mm;
    }
    __syncthreads();
    m = red[0];
    __syncthreads();

    float s = 0.f;
    for (int v = tid; v < V; v += 1024) s += expf(lg[v] - m);
#pragma unroll
    for (int off = 32; off; off >>= 1) s += __shfl_down(s, off);
    if ((tid & 63) == 0) red[tid >> 6] = s;
    __syncthreads();
    if (tid == 0) {
        float t = 0.f;
        for (int w = 0; w < 16; ++w) t += red[w];
        red[0] = t;
    }
    __syncthreads();
    float lse = m + logf(red[0]);

    for (int v = tid; v < V; v += 1024) out[v] = lg[v] - lse;
}

extern "C" void kernel_launch(void* const* d_in, const int* in_sizes, int n_in,
                              void* d_out, int out_size, void* d_ws, size_t ws_size,
                              hipStream_t stream) {
    const int*   tok  = (const int*)d_in[0];
    const float* hid  = (const float*)d_in[1];   // [2,1,H]
    const float* enc  = (const float*)d_in[2];   // [L,H]
    const float* emb  = (const float*)d_in[3];   // [V,H]
    const float* Wq   = (const float*)d_in[4];
    const float* Wk   = (const float*)d_in[5];
    const float* wv   = (const float*)d_in[6];
    const float* Wih0 = (const float*)d_in[7];
    const float* Whh0 = (const float*)d_in[8];
    const float* bih0 = (const float*)d_in[9];
    const float* bhh0 = (const float*)d_in[10];
    const float* Wih1 = (const float*)d_in[11];
    const float* Whh1 = (const float*)d_in[12];
    const float* bih1 = (const float*)d_in[13];
    const float* bhh1 = (const float*)d_in[14];
    const float* Wd   = (const float*)d_in[15];  // [H,V]
    const float* bd   = (const float*)d_in[16];
    float* out = (float*)d_out;                  // [V logp][H h0n][H h1n]
    float* ws  = (float*)d_ws;

    hipMemsetAsync(ws, 0, WS_FLOATS * sizeof(float), stream);

    k_embed<<<4, 256, 0, stream>>>(tok, emb, ws);
    k_qw<<<dim3(4, 16), 256, 0, stream>>>(Wq, hid, ws);
    k_gemm_scores<<<dim3(L / 64, H / 64), 256, 0, stream>>>(enc, Wk, wv, ws);
    k_softmax<<<1, 1024, 0, stream>>>(ws);
    k_context<<<dim3(4, 32), 256, 0, stream>>>(enc, ws);

    k_gates<<<1536, 256, 0, stream>>>(Wih0, Whh0, bih0, bhh0,
                                      ws + OFF_X, 2 * H, hid,
                                      ws + OFF_GI0, ws + OFF_GH0);
    k_combine<<<4, 256, 0, stream>>>(ws + OFF_GI0, ws + OFF_GH0, hid, out + V);

    k_gates<<<1536, 256, 0, stream>>>(Wih1, Whh1, bih1, bhh1,
                                      out + V, H, hid + H,
                                      ws + OFF_GI1, ws + OFF_GH1);
    k_combine<<<4, 256, 0, stream>>>(ws + OFF_GI1, ws + OFF_GH1, hid + H, out + V + H);

    k_logits<<<dim3((V + 255) / 256, 8), 256, 0, stream>>>(Wd, bd, out + V + H, ws);
    k_logsoftmax<<<1, 1024, 0, stream>>>(ws + OFF_LOGITS, out);
}

// Round 2
// 530.764 us; speedup vs baseline: 1.1657x; 1.1657x over previous
//
#include <hip/hip_runtime.h>
#include <hip/hip_bf16.h>

#define H  1024
#define L  4096
#define V  50257

// workspace layout (floats)
#define OFF_QW     0                    // 1024   query @ Wq
#define OFF_SCORES 1024                 // 4096   raw scores (pre-softmax)
#define OFF_X      5120                 // 2048   x = concat(context, emb_relu)
#define OFF_GI0    7168                 // 3072
#define OFF_GH0    10240                // 3072
#define OFF_GI1    13312                // 3072
#define OFF_GH1    16384                // 3072
#define OFF_LOGITS 19456                // V
#define ZERO_FLOATS (OFF_LOGITS + V)    // 69713 floats zeroed per call
#define OFF_WKT_BYTES 278880            // 16B-aligned; bf16 WkT[1024][1024] = 2 MB

typedef __bf16 bf8   __attribute__((ext_vector_type(8)));
typedef float  f32x16 __attribute__((ext_vector_type(16)));

__device__ inline unsigned int pack_bf16x2(float lo, float hi) {
    unsigned int ulo = __builtin_bit_cast(unsigned int, lo);
    unsigned int uhi = __builtin_bit_cast(unsigned int, hi);
    return ((uhi + 0x8000u) & 0xFFFF0000u) | ((ulo + 0x8000u) >> 16);
}
__device__ inline unsigned short cvt_bf16(float f) {
    unsigned int u = __builtin_bit_cast(unsigned int, f);
    return (unsigned short)((u + 0x8000u) >> 16);
}

// ============ prep: embed+relu | qW = q@Wq | WkT bf16 transpose ============
// blocks [0,4): embed; [4,68): qw (4 j-blocks x 16 k-splits); [68,1092): WkT tiles
__global__ __launch_bounds__(256) void k_prep(const int* __restrict__ tok,
                                              const float* __restrict__ emb,
                                              const float* __restrict__ hid,
                                              const float* __restrict__ Wq,
                                              const float* __restrict__ Wk,
                                              float* __restrict__ ws,
                                              unsigned short* __restrict__ wkT) {
    __shared__ float tile[32][33];
    const int b = blockIdx.x, t = threadIdx.x;
    if (b < 4) {
        int j = b * 256 + t;
        float v = emb[(size_t)tok[0] * H + j];
        ws[OFF_X + H + j] = fmaxf(v, 0.f);
    } else if (b < 68) {
        int bb = b - 4;
        int j = (bb & 3) * 256 + t;
        int i0 = (bb >> 2) * 64;
        const float* q = hid + H;
        float acc = 0.f;
#pragma unroll 8
        for (int i = i0; i < i0 + 64; ++i) acc += q[i] * Wq[i * H + j];
        atomicAdd(&ws[OFF_QW + j], acc);
    } else {
        int tt = b - 68;              // 32x32 grid of 32x32 tiles
        int tk = tt & 31, tn = tt >> 5;
        int c = t & 31, r0 = t >> 5;
#pragma unroll
        for (int rr = 0; rr < 4; ++rr) {
            int r = r0 + rr * 8;
            tile[r][c] = Wk[(size_t)(tk * 32 + r) * H + tn * 32 + c];
        }
        __syncthreads();
#pragma unroll
        for (int rr = 0; rr < 4; ++rr) {
            int rn = r0 + rr * 8;     // output row n, col k; read tile[ck][rn]
            wkT[(size_t)(tn * 32 + rn) * H + tk * 32 + c] = cvt_bf16(tile[c][rn]);
        }
    }
}

// ============ scores GEMM: bf16 MFMA, tile 64x128, K-step 32 ============
// grid (L/64=64, H/128=8), 256 threads (4 waves). Epilogue: tanh(+qW)*wv
// reduced over n, atomicAdd into raw scores.
__global__ __launch_bounds__(256) void k_gemm_scores(const float* __restrict__ enc,
                                                     const unsigned short* __restrict__ wkT,
                                                     const float* __restrict__ wv,
                                                     float* __restrict__ ws) {
    __shared__ unsigned short As[64][40];   // [m][k] bf16, +8 pad
    __shared__ unsigned short Bs[128][40];  // [n][k] bf16
    const int t = threadIdx.x, lane = t & 63, w = t >> 6;
    const int m0 = blockIdx.x * 64, n0 = blockIdx.y * 128;

    f32x16 acc0 = {}, acc1 = {};

    const int ar = t >> 2, akq = (t & 3) * 8;     // A: 64x32 fp32 -> bf16
    const int bn = t >> 1, bkh = (t & 1) * 16;    // B: 128x32 bf16 copy

    const int r0 = (w & 1) * 32, c0 = (w >> 1) * 64;
    const int mrow = r0 + (lane & 31);
    const int nrow0 = c0 + (lane & 31), nrow1 = nrow0 + 32;

    for (int k0 = 0; k0 < H; k0 += 32) {
        float4 fa = *(const float4*)(enc + (size_t)(m0 + ar) * H + k0 + akq);
        float4 fb = *(const float4*)(enc + (size_t)(m0 + ar) * H + k0 + akq + 4);
        uint4 wb0 = *(const uint4*)(wkT + (size_t)(n0 + bn) * H + k0 + bkh);
        uint4 wb1 = *(const uint4*)(wkT + (size_t)(n0 + bn) * H + k0 + bkh + 8);
        __syncthreads();   // previous-iter LDS reads done before overwrite
        uint4 pa;
        pa.x = pack_bf16x2(fa.x, fa.y); pa.y = pack_bf16x2(fa.z, fa.w);
        pa.z = pack_bf16x2(fb.x, fb.y); pa.w = pack_bf16x2(fb.z, fb.w);
        *(uint4*)&As[ar][akq] = pa;
        *(uint4*)&Bs[bn][bkh] = wb0;
        *(uint4*)&Bs[bn][bkh + 8] = wb1;
        __syncthreads();
#pragma unroll
        for (int kk = 0; kk < 2; ++kk) {
            int kb = kk * 16 + (lane >> 5) * 8;
            bf8 a  = *(const bf8*)&As[mrow][kb];
            bf8 b0 = *(const bf8*)&Bs[nrow0][kb];
            bf8 b1 = *(const bf8*)&Bs[nrow1][kb];
            acc0 = __builtin_amdgcn_mfma_f32_32x32x16_bf16(a, b0, acc0, 0, 0, 0);
            acc1 = __builtin_amdgcn_mfma_f32_32x32x16_bf16(a, b1, acc1, 0, 0, 0);
        }
    }

    // epilogue: s[l] += sum_n tanh(acc+qW[n])*wv[n]
    const int n_a = n0 + nrow0, n_b = n0 + nrow1;
    float qwa = ws[OFF_QW + n_a], qwb = ws[OFF_QW + n_b];
    float wva = wv[n_a], wvb = wv[n_b];
    const int rbase = m0 + r0 + 4 * (lane >> 5);
#pragma unroll
    for (int reg = 0; reg < 16; ++reg) {
        float s = tanhf(acc0[reg] + qwa) * wva + tanhf(acc1[reg] + qwb) * wvb;
#pragma unroll
        for (int msk = 1; msk < 32; msk <<= 1) s += __shfl_xor(s, msk);
        if ((lane & 31) == 0) {
            int l = rbase + (reg & 3) + 8 * (reg >> 2);
            atomicAdd(&ws[OFF_SCORES + l], s);
        }
    }
}

// ============ context with inline softmax (shift-invariant per block) ====
// grid (4 h-blocks, 32 l-splits of 128)
__global__ __launch_bounds__(256) void k_context(const float* __restrict__ enc,
                                                 float* __restrict__ ws) {
    __shared__ float red[4];
    const int t = threadIdx.x;
    const float* sc = ws + OFF_SCORES;

    float m = -1e30f;
#pragma unroll
    for (int i = 0; i < 16; ++i) m = fmaxf(m, sc[t + i * 256]);
#pragma unroll
    for (int msk = 1; msk < 64; msk <<= 1) m = fmaxf(m, __shfl_xor(m, msk));
    if ((t & 63) == 0) red[t >> 6] = m;
    __syncthreads();
    m = fmaxf(fmaxf(red[0], red[1]), fmaxf(red[2], red[3]));
    __syncthreads();

    float s = 0.f;
#pragma unroll
    for (int i = 0; i < 16; ++i) s += expf(sc[t + i * 256] - m);
#pragma unroll
    for (int msk = 1; msk < 64; msk <<= 1) s += __shfl_xor(s, msk);
    if ((t & 63) == 0) red[t >> 6] = s;
    __syncthreads();
    float inv = 1.f / (red[0] + red[1] + red[2] + red[3]);

    const int h = blockIdx.x * 256 + t;
    const int l0 = blockIdx.y * 128;
    float acc = 0.f;
#pragma unroll 4
    for (int l = l0; l < l0 + 128; ++l)
        acc += expf(sc[l] - m) * enc[(size_t)l * H + h];
    atomicAdd(&ws[OFF_X + h], acc * inv);
}

// ============ GRU layer-0 gates (generic) ============
__global__ __launch_bounds__(256) void k_gates(const float* __restrict__ Wih,
                                               const float* __restrict__ Whh,
                                               const float* __restrict__ bih,
                                               const float* __restrict__ bhh,
                                               const float* __restrict__ x, int Cx,
                                               const float* __restrict__ h,
                                               float* __restrict__ gi,
                                               float* __restrict__ gh) {
    int b = blockIdx.x;
    bool isH = (b >= 768);
    int row  = (isH ? b - 768 : b) * 4 + (threadIdx.x >> 6);
    int lane = threadIdx.x & 63;
    const float* W    = isH ? Whh : Wih;
    const float* v    = isH ? h : x;
    const float* bias = isH ? bhh : bih;
    int C       = isH ? H : Cx;
    float* out  = isH ? gh : gi;

    const float4* Wr = (const float4*)(W + (size_t)row * C);
    const float4* v4 = (const float4*)v;
    float acc = 0.f;
    int n4 = C >> 2;
    for (int c = lane; c < n4; c += 64) {
        float4 wv4 = Wr[c], xx = v4[c];
        acc += wv4.x * xx.x + wv4.y * xx.y + wv4.z * xx.z + wv4.w * xx.w;
    }
#pragma unroll
    for (int off = 32; off; off >>= 1) acc += __shfl_down(acc, off);
    if (lane == 0) out[row] = acc + bias[row];
}

// ============ GRU layer-1 gates, fused combine0 prologue ============
__global__ __launch_bounds__(256) void k_gates1(const float* __restrict__ Wih,
                                                const float* __restrict__ Whh,
                                                const float* __restrict__ bih,
                                                const float* __restrict__ bhh,
                                                const float* __restrict__ gi0,
                                                const float* __restrict__ gh0,
                                                const float* __restrict__ hid,
                                                float* __restrict__ h0n_out,
                                                float* __restrict__ gi,
                                                float* __restrict__ gh) {
    const int b = blockIdx.x, t = threadIdx.x;
    const int lane = t & 63;
    if (b < 768) {
        __shared__ float xs[H];
#pragma unroll
        for (int jj = 0; jj < 4; ++jj) {
            int j = t + jj * 256;
            float r = 1.f / (1.f + expf(-(gi0[j] + gh0[j])));
            float z = 1.f / (1.f + expf(-(gi0[H + j] + gh0[H + j])));
            float n = tanhf(gi0[2 * H + j] + r * gh0[2 * H + j]);
            float h0 = (1.f - z) * n + z * hid[j];
            xs[j] = h0;
            if (b == 0) h0n_out[j] = h0;
        }
        __syncthreads();
        int row = b * 4 + (t >> 6);
        const float4* Wr = (const float4*)(Wih + (size_t)row * H);
        float acc = 0.f;
        for (int c = lane; c < H / 4; c += 64) {
            float4 wv4 = Wr[c];
            float4 xx = *(const float4*)&xs[c * 4];
            acc += wv4.x * xx.x + wv4.y * xx.y + wv4.z * xx.z + wv4.w * xx.w;
        }
#pragma unroll
        for (int off = 32; off; off >>= 1) acc += __shfl_down(acc, off);
        if (lane == 0) gi[row] = acc + bih[row];
    } else {
        int row = (b - 768) * 4 + (t >> 6);
        const float4* Wr = (const float4*)(Whh + (size_t)row * H);
        const float4* h4 = (const float4*)(hid + H);
        float acc = 0.f;
        for (int c = lane; c < H / 4; c += 64) {
            float4 wv4 = Wr[c], xx = h4[c];
            acc += wv4.x * xx.x + wv4.y * xx.y + wv4.z * xx.z + wv4.w * xx.w;
        }
#pragma unroll
        for (int off = 32; off; off >>= 1) acc += __shfl_down(acc, off);
        if (lane == 0) gh[row] = acc + bhh[row];
    }
}

// ============ logits, fused combine1 prologue ============
// grid (197, 8 k-splits of 128)
__global__ __launch_bounds__(256) void k_logits(const float* __restrict__ Wd,
                                                const float* __restrict__ bd,
                                                const float* __restrict__ gi1,
                                                const float* __restrict__ gh1,
                                                const float* __restrict__ hid,
                                                float* __restrict__ h1n_out,
                                                float* __restrict__ ws) {
    __shared__ float h1s[H];
    const int t = threadIdx.x;
#pragma unroll
    for (int jj = 0; jj < 4; ++jj) {
        int j = t + jj * 256;
        float r = 1.f / (1.f + expf(-(gi1[j] + gh1[j])));
        float z = 1.f / (1.f + expf(-(gi1[H + j] + gh1[H + j])));
        float n = tanhf(gi1[2 * H + j] + r * gh1[2 * H + j]);
        float h1 = (1.f - z) * n + z * hid[H + j];
        h1s[j] = h1;
        if (blockIdx.x == 0 && blockIdx.y == 0) h1n_out[j] = h1;
    }
    __syncthreads();
    int v = blockIdx.x * 256 + t;
    if (v >= V) return;
    int k0 = blockIdx.y * 128;
    float acc = (blockIdx.y == 0) ? bd[v] : 0.f;
    const float* Wp = Wd + (size_t)k0 * V + v;
#pragma unroll 8
    for (int k = 0; k < 128; ++k) acc += h1s[k0 + k] * Wp[(size_t)k * V];
    atomicAdd(&ws[OFF_LOGITS + v], acc);
}

// ============ log_softmax over V ============
__global__ __launch_bounds__(1024) void k_logsoftmax(const float* __restrict__ lg,
                                                     float* __restrict__ out) {
    __shared__ float red[16];
    const int tid = threadIdx.x;

    float m = -1e30f;
    for (int v = tid; v < V; v += 1024) m = fmaxf(m, lg[v]);
#pragma unroll
    for (int off = 32; off; off >>= 1) m = fmaxf(m, __shfl_down(m, off));
    if ((tid & 63) == 0) red[tid >> 6] = m;
    __syncthreads();
    if (tid == 0) {
        float mm = red[0];
        for (int w = 1; w < 16; ++w) mm = fmaxf(mm, red[w]);
        red[0] = mm;
    }
    __syncthreads();
    m = red[0];
    __syncthreads();

    float s = 0.f;
    for (int v = tid; v < V; v += 1024) s += expf(lg[v] - m);
#pragma unroll
    for (int off = 32; off; off >>= 1) s += __shfl_down(s, off);
    if ((tid & 63) == 0) red[tid >> 6] = s;
    __syncthreads();
    if (tid == 0) {
        float tt = 0.f;
        for (int w = 0; w < 16; ++w) tt += red[w];
        red[0] = tt;
    }
    __syncthreads();
    float lse = m + logf(red[0]);

    for (int v = tid; v < V; v += 1024) out[v] = lg[v] - lse;
}

extern "C" void kernel_launch(void* const* d_in, const int* in_sizes, int n_in,
                              void* d_out, int out_size, void* d_ws, size_t ws_size,
                              hipStream_t stream) {
    const int*   tok  = (const int*)d_in[0];
    const float* hid  = (const float*)d_in[1];   // [2,1,H]
    const float* enc  = (const float*)d_in[2];   // [L,H]
    const float* emb  = (const float*)d_in[3];   // [V,H]
    const float* Wq   = (const float*)d_in[4];
    const float* Wk   = (const float*)d_in[5];
    const float* wv   = (const float*)d_in[6];
    const float* Wih0 = (const float*)d_in[7];
    const float* Whh0 = (const float*)d_in[8];
    const float* bih0 = (const float*)d_in[9];
    const float* bhh0 = (const float*)d_in[10];
    const float* Wih1 = (const float*)d_in[11];
    const float* Whh1 = (const float*)d_in[12];
    const float* bih1 = (const float*)d_in[13];
    const float* bhh1 = (const float*)d_in[14];
    const float* Wd   = (const float*)d_in[15];  // [H,V]
    const float* bd   = (const float*)d_in[16];
    float* out = (float*)d_out;                  // [V logp][H h0n][H h1n]
    float* ws  = (float*)d_ws;
    unsigned short* wkT = (unsigned short*)((char*)d_ws + OFF_WKT_BYTES);

    hipMemsetAsync(ws, 0, ZERO_FLOATS * sizeof(float), stream);

    k_prep<<<1092, 256, 0, stream>>>(tok, emb, hid, Wq, Wk, ws, wkT);
    k_gemm_scores<<<dim3(L / 64, H / 128), 256, 0, stream>>>(enc, wkT, wv, ws);
    k_context<<<dim3(4, 32), 256, 0, stream>>>(enc, ws);
    k_gates<<<1536, 256, 0, stream>>>(Wih0, Whh0, bih0, bhh0,
                                      ws + OFF_X, 2 * H, hid,
                                      ws + OFF_GI0, ws + OFF_GH0);
    k_gates1<<<1536, 256, 0, stream>>>(Wih1, Whh1, bih1, bhh1,
                                       ws + OFF_GI0, ws + OFF_GH0, hid,
                                       out + V, ws + OFF_GI1, ws + OFF_GH1);
    k_logits<<<dim3((V + 255) / 256, 8), 256, 0, stream>>>(Wd, bd,
                                       ws + OFF_GI1, ws + OFF_GH1, hid,
                                       out + V + H, ws);
    k_logsoftmax<<<1, 1024, 0, stream>>>(ws + OFF_LOGITS, out);
}